// Round 4
// baseline (496.240 us; speedup 1.0000x reference)
//
#include <hip/hip_runtime.h>
#include <stdint.h>

#define B_  8
#define C_  256
#define H_  4
#define D_  64
#define N_  4096
#define C2_ 512
#define NT_ (B_*N_)   // 32768 total (b,n) columns

typedef __attribute__((ext_vector_type(8))) short short8;
typedef __attribute__((ext_vector_type(4))) short short4_t;
typedef __attribute__((ext_vector_type(4))) float f32x4;

__device__ __forceinline__ short f2bf(float f) {
  union { float f; unsigned u; } v; v.f = f;
  unsigned r = v.u + 0x7fffu + ((v.u >> 16) & 1u);
  return (short)(r >> 16);
}
__device__ __forceinline__ float bfraw2f(unsigned hi_bits) {
  union { unsigned u; float f; } v; v.u = hi_bits;
  return v.f;
}
__device__ __forceinline__ unsigned fbits(float f) {
  union { float f; unsigned u; } v; v.f = f; return v.u;
}

#if __has_builtin(__builtin_amdgcn_exp2f)
#define EXP2(x) __builtin_amdgcn_exp2f(x)
#else
#define EXP2(x) exp2f(x)
#endif

#define GLOAD16(g, l) __builtin_amdgcn_global_load_lds( \
    (const __attribute__((address_space(1))) void*)(g), \
    (__attribute__((address_space(3))) void*)(l), 16, 0, 0)

// ---------------------------------------------------------------------------
// Weight prep: Wcat = [w1a | w1b@wm] bf16, beff = b1 + w1b@bm, zero stats
// ---------------------------------------------------------------------------
__global__ __launch_bounds__(256) void prep_wcat(
    const float* __restrict__ w1, const float* __restrict__ wm,
    const float* __restrict__ b1, const float* __restrict__ bm,
    short* __restrict__ wcat, float* __restrict__ beff, float* __restrict__ stats)
{
  int i = blockIdx.x, j = threadIdx.x;
  wcat[(size_t)i*512 + j] = f2bf(w1[(size_t)i*512 + j]);
  float acc = 0.f;
  for (int c = 0; c < 256; ++c)
    acc += w1[(size_t)i*512 + 256 + c] * wm[(size_t)c*256 + j];
  wcat[(size_t)i*512 + 256 + j] = f2bf(acc);
  if (j == 0) {
    float a = b1[i];
    for (int c = 0; c < 256; ++c) a += w1[(size_t)i*512 + 256 + c] * bm[c];
    beff[i] = a;
  }
  if (blockIdx.x < 4) stats[blockIdx.x*256 + j] = 0.f;
}

// one launch for all four weight conversions (wq/wk/wv = 65536, w2 = 131072)
__global__ __launch_bounds__(256) void cvt4_bf16(
    const float* __restrict__ s0, const float* __restrict__ s1,
    const float* __restrict__ s2, const float* __restrict__ s3,
    short* __restrict__ d0, short* __restrict__ d1,
    short* __restrict__ d2, short* __restrict__ d3)
{
  int i = blockIdx.x*256 + threadIdx.x;
  if (i < 65536)        d0[i]          = f2bf(s0[i]);
  else if (i < 131072)  d1[i - 65536]  = f2bf(s1[i - 65536]);
  else if (i < 196608)  d2[i - 131072] = f2bf(s2[i - 131072]);
  else                  d3[i - 196608] = f2bf(s3[i - 196608]);
}

// ---------------------------------------------------------------------------
// Transpose+convert: m1[b,c,n] -> xt1[b,n,c] (ld 512, low 256), m2 -> mt2 (ld 256)
// ---------------------------------------------------------------------------
__global__ __launch_bounds__(256) void transpose_cvt(
    const float* __restrict__ m1, const float* __restrict__ m2,
    short* __restrict__ xt1, short* __restrict__ mt2)
{
  __shared__ float tile[32][33];
  int z = blockIdx.z;            // 0..15
  int b = z >> 1, which = z & 1;
  const float* src = which ? m2 : m1;
  short* dst = which ? mt2 : xt1;
  int ldd = which ? 256 : 512;
  int c0 = blockIdx.y*32, n0 = blockIdx.x*32;
  int tx = threadIdx.x & 31, ty = threadIdx.x >> 5;   // ty 0..7
  for (int r = 0; r < 4; ++r) {
    int c = c0 + ty + r*8;
    tile[ty + r*8][tx] = src[((size_t)b*256 + c)*4096 + n0 + tx];
  }
  __syncthreads();
  for (int r = 0; r < 4; ++r) {
    int n = n0 + ty + r*8;
    dst[((size_t)b*4096 + n)*ldd + c0 + tx] = f2bf(tile[tx][ty + r*8]);
  }
}

// ---------------------------------------------------------------------------
// Generic 128x128-tile bf16 GEMM, B^T form: Out[i,j] = sum_k A[i,k]*B[j,k]+bias[i]
// MODE 0: QK projection -> out[( (i>>6)*4096 + j)*64 + (i&63)]  (per-batch z), *scale after bias
// MODE 1: V projection  -> out[i*4096 + j]                      (per-batch z)
// MODE 2: h GEMM        -> out[j*512 + i]  (transposed store)
// MODE 3: final         -> fp32 out[((j>>12)*256+i)*4096 + (j&4095)] += resid
// ---------------------------------------------------------------------------
template<int MODE>
__global__ __launch_bounds__(256) void gemm_bt(
    const short* __restrict__ A, int lda,
    const short* __restrict__ Bm, int ldb,
    const float* __restrict__ bias, float scale, int Kc,
    void* __restrict__ OutP, const float* __restrict__ resid)
{
  __shared__ __align__(16) short As[128*64];
  __shared__ __align__(16) short Bs[128*64];
  const int tid  = threadIdx.x;
  const int wave = tid >> 6, lane = tid & 63;
  const int it = blockIdx.y, jt = blockIdx.x, bz = blockIdx.z;
  const int i0 = it*128, j0 = jt*128;
  const short* Bb = Bm + (size_t)bz * 4096 * ldb;   // z only used for MODE 0/1
  const int wi = wave >> 1, wj = wave & 1;
  const int l15 = lane & 15, lg = lane >> 4;

  f32x4 acc[4][4] = {};

  for (int k0 = 0; k0 < Kc; k0 += 64) {
    __syncthreads();
    for (int s = 0; s < 4; ++s) {
      int flat = s*256 + tid;
      int row = flat >> 3, l8 = flat & 7;
      GLOAD16(A  + (size_t)(i0 + row)*lda + k0 + l8*8, &As[(s*256 + wave*64)*8]);
      GLOAD16(Bb + (size_t)(j0 + row)*ldb + k0 + l8*8, &Bs[(s*256 + wave*64)*8]);
    }
    __syncthreads();
    for (int ks = 0; ks < 2; ++ks) {
      short8 af[4], bf[4];
      for (int mt = 0; mt < 4; ++mt)
        af[mt] = *(const short8*)&As[(wi*64 + mt*16 + l15)*64 + ks*32 + lg*8];
      for (int nt = 0; nt < 4; ++nt)
        bf[nt] = *(const short8*)&Bs[(wj*64 + nt*16 + l15)*64 + ks*32 + lg*8];
      for (int mt = 0; mt < 4; ++mt)
        for (int nt = 0; nt < 4; ++nt)
          acc[mt][nt] = __builtin_amdgcn_mfma_f32_16x16x32_bf16(af[mt], bf[nt], acc[mt][nt], 0, 0, 0);
    }
  }

  for (int mt = 0; mt < 4; ++mt)
    for (int nt = 0; nt < 4; ++nt)
      for (int r = 0; r < 4; ++r) {
        int i = i0 + wi*64 + mt*16 + lg*4 + r;
        int j = j0 + wj*64 + nt*16 + l15;
        float v = acc[mt][nt][r] + bias[i];
        if (MODE == 0) {
          v *= scale;
          short* out = (short*)OutP + (size_t)bz*C_*N_;
          out[((size_t)((i >> 6)*4096 + j))*64 + (i & 63)] = f2bf(v);
        } else if (MODE == 1) {
          short* out = (short*)OutP + (size_t)bz*C_*N_;
          out[(size_t)i*4096 + j] = f2bf(v);
        } else if (MODE == 2) {
          ((short*)OutP)[(size_t)j*512 + i] = f2bf(v);
        } else {
          size_t oi = ((size_t)(j >> 12)*256 + i)*4096 + (j & 4095);
          ((float*)OutP)[oi] = v + resid[oi];
        }
      }
}

// ---------------------------------------------------------------------------
// Flash attention v4: grid (N/128, B*H) = 1024 blocks (4/CU, 16 waves/CU),
// 256 thr = 4 waves x 32 q-rows. S^T = K·Q^T (P exits MFMA in A-fragment
// form). K/V double-buffered in LDS, XOR-swizzled chunks (conflict-free).
// Q pre-scaled by log2(e)/8 -> exp2. No max-subtraction (scores bounded).
// ---------------------------------------------------------------------------
__global__ __launch_bounds__(256, 4) void flash_attn(
    const short* __restrict__ qb, const short* __restrict__ kb,
    const short* __restrict__ vb, short* __restrict__ xt1)
{
  __shared__ __align__(16) short K_lds[2][64*64];   // chunk (row,dc) at row*8 + (dc ^ (row&7))
  __shared__ __align__(16) short V_lds[2][64*64];   // chunk (d,mc)  at d*8 + (mc ^ (d&7))
  const int tid = threadIdx.x, wave = tid >> 6, lane = tid & 63;
  const int l15 = lane & 15, lg = lane >> 4;
  const int bh = blockIdx.y, qt = blockIdx.x;
  const int b = bh >> 2, h = bh & 3;
  const short* qbase = qb + (size_t)bh*4096*64;
  const short* kbase = kb + (size_t)bh*4096*64;
  const short* vbase = vb + ((size_t)b*256 + h*64)*4096;
  const int q0 = qt*128 + wave*32;

  // staging addresses (chunk c = s*256 + tid), swizzle x = (c&7) ^ (row&7)
  int c0 = tid, c1 = 256 + tid;
  int row0 = c0 >> 3, x0 = (c0 & 7) ^ (row0 & 7);
  int row1 = c1 >> 3, x1 = (c1 & 7) ^ (row1 & 7);
  const short* kg0 = kbase + row0*64 + x0*8;
  const short* kg1 = kbase + row1*64 + x1*8;
  const short* vg0 = vbase + (size_t)row0*4096 + x0*8;
  const short* vg1 = vbase + (size_t)row1*4096 + x1*8;
  const unsigned ldsA = (unsigned)((wave*64)*8);
  const unsigned ldsB = (unsigned)((256 + wave*64)*8);

  // loop-invariant LDS read offsets
  unsigned kOff[4][2];
  for (int ct = 0; ct < 4; ++ct) {
    int row = ct*16 + l15;
    for (int hf = 0; hf < 2; ++hf)
      kOff[ct][hf] = (unsigned)(row*64 + (((hf*4 + lg) ^ (row & 7))*8));
  }
  unsigned vOff[2][4][2];
  for (int p = 0; p < 2; ++p)
    for (int dt = 0; dt < 4; ++dt) {
      int d = dt*16 + l15;
      int mc1 = p*4 + (lg >> 1), mc2 = mc1 + 2;
      vOff[p][dt][0] = (unsigned)((d*8 + (mc1 ^ (d & 7)))*8 + (lg & 1)*4);
      vOff[p][dt][1] = (unsigned)((d*8 + (mc2 ^ (d & 7)))*8 + (lg & 1)*4);
    }

  short8 qf[2][2];
  for (int rt = 0; rt < 2; ++rt) {
    int q = q0 + rt*16 + l15;
    for (int hf = 0; hf < 2; ++hf)
      qf[rt][hf] = *(const short8*)(qbase + (size_t)q*64 + hf*32 + lg*8);
  }

  f32x4 o[2][4] = {};          // [rt][dt]: rows q=lg*4+r, col d=l15
  f32x4 rs4[2] = {};

  // preload tile 0 into buffer 0
  GLOAD16(kg0, &K_lds[0][ldsA]);
  GLOAD16(kg1, &K_lds[0][ldsB]);
  GLOAD16(vg0, &V_lds[0][ldsA]);
  GLOAD16(vg1, &V_lds[0][ldsB]);

  for (int itv = 0; itv < 64; ++itv) {
    __syncthreads();   // drains this wave's in-flight loads => buf[cur] ready for all
    const int cur = itv & 1, nxt = cur ^ 1;
    const size_t mN = (size_t)(((itv + 1) & 63) * 64);  // wraps to 0 on last iter (harmless refetch)
    GLOAD16(kg0 + mN*64, &K_lds[nxt][ldsA]);
    GLOAD16(kg1 + mN*64, &K_lds[nxt][ldsB]);
    GLOAD16(vg0 + mN,    &V_lds[nxt][ldsA]);
    GLOAD16(vg1 + mN,    &V_lds[nxt][ldsB]);

    const short* Kb = &K_lds[cur][0];
    const short* Vb = &V_lds[cur][0];

    // K fragments: lane row m = ct*16+l15, d-chunk deswizzled
    short8 kf[4][2];
    for (int ct = 0; ct < 4; ++ct)
      for (int hf = 0; hf < 2; ++hf)
        kf[ct][hf] = *(const short8*)(Kb + kOff[ct][hf]);
    // V fragments: lane d = dt*16+l15; k-slot (lg,j) -> m = p*32+(j>>2)*16+lg*4+(j&3)
    short8 vf[2][4];
    for (int p = 0; p < 2; ++p)
      for (int dt = 0; dt < 4; ++dt) {
        union { short8 v; short4_t h[2]; } u;
        u.h[0] = *(const short4_t*)(Vb + vOff[p][dt][0]);
        u.h[1] = *(const short4_t*)(Vb + vOff[p][dt][1]);
        vf[p][dt] = u.v;
      }

    for (int rt = 0; rt < 2; ++rt) {
      // S^T tiles: D[m][q], lane col q=l15, rows m=ct*16+lg*4+r
      f32x4 sc[4];
      for (int ct = 0; ct < 4; ++ct) {
        f32x4 s = {0.f, 0.f, 0.f, 0.f};
        s = __builtin_amdgcn_mfma_f32_16x16x32_bf16(kf[ct][0], qf[rt][0], s, 0, 0, 0);
        s = __builtin_amdgcn_mfma_f32_16x16x32_bf16(kf[ct][1], qf[rt][1], s, 0, 0, 0);
        sc[ct] = s;
      }
      // exp2 + rowsum + truncating pack into A-fragments (k-perm matches vf)
      for (int p = 0; p < 2; ++p) {
        union { short8 v; unsigned u[4]; } pf;
        for (int idx = 0; idx < 2; ++idx) {
          f32x4 sv = sc[2*p + idx];
          f32x4 ev;
          ev[0] = EXP2(sv[0]); ev[1] = EXP2(sv[1]);
          ev[2] = EXP2(sv[2]); ev[3] = EXP2(sv[3]);
          rs4[rt] += ev;
          pf.u[idx*2 + 0] = __builtin_amdgcn_perm(fbits(ev[1]), fbits(ev[0]), 0x07060302u);
          pf.u[idx*2 + 1] = __builtin_amdgcn_perm(fbits(ev[3]), fbits(ev[2]), 0x07060302u);
        }
        for (int dt = 0; dt < 4; ++dt)
          o[rt][dt] = __builtin_amdgcn_mfma_f32_16x16x32_bf16(pf.v, vf[p][dt], o[rt][dt], 0, 0, 0);
      }
    }
  }

  // reduce rowsums across lg (each lane: q = l15 within its rt tile)
  float rsI[2];
  for (int rt = 0; rt < 2; ++rt) {
    float v = (rs4[rt][0] + rs4[rt][1]) + (rs4[rt][2] + rs4[rt][3]);
    v += __shfl_xor(v, 16);
    v += __shfl_xor(v, 32);
    rsI[rt] = 1.0f / v;
  }
  for (int rt = 0; rt < 2; ++rt) {
    float invq[4];
    for (int r = 0; r < 4; ++r) invq[r] = __shfl(rsI[rt], lg*4 + r);
    for (int dt = 0; dt < 4; ++dt)
      for (int r = 0; r < 4; ++r) {
        int q = q0 + rt*16 + lg*4 + r;
        int d = dt*16 + l15;
        float val = o[rt][dt][r] * invq[r];
        xt1[((size_t)b*4096 + q)*512 + 256 + h*64 + d] = f2bf(val);
      }
  }
}

// ---------------------------------------------------------------------------
// BN stats: per-channel sum/sumsq over 32768 rows of h_t[32768][512]
// ---------------------------------------------------------------------------
__global__ __launch_bounds__(256) void bn_stats(const short* __restrict__ ht,
                                                float* __restrict__ stats)
{
  int p = blockIdx.x, t = threadIdx.x;
  int c0 = t*2;
  float s0=0.f, s1=0.f, q0=0.f, q1=0.f;
  for (int r = 0; r < 256; ++r) {
    size_t row = (size_t)p*256 + r;
    unsigned v = *(const unsigned*)&ht[row*512 + c0];
    float x0 = bfraw2f(v << 16);
    float x1 = bfraw2f(v & 0xffff0000u);
    s0 += x0; q0 += x0*x0; s1 += x1; q1 += x1*x1;
  }
  atomicAdd(&stats[c0],       s0);
  atomicAdd(&stats[c0+1],     s1);
  atomicAdd(&stats[512+c0],   q0);
  atomicAdd(&stats[512+c0+1], q1);
}

__global__ void bn_final(const float* __restrict__ stats,
                         const float* __restrict__ gamma, const float* __restrict__ beta,
                         float* __restrict__ ss)
{
  int c = blockIdx.x*256 + threadIdx.x;
  if (c >= 512) return;
  float mean = stats[c] * (1.f/32768.f);
  float var  = stats[512+c] * (1.f/32768.f) - mean*mean;
  float sc = gamma[c] * rsqrtf(var + 1e-5f);
  ss[c] = sc;
  ss[512+c] = beta[c] - mean*sc;
}

__global__ __launch_bounds__(256) void relu_affine(short* __restrict__ ht,
                                                   const float* __restrict__ ss)
{
  size_t idx = (size_t)blockIdx.x*256 + threadIdx.x;   // pairs; 8388608 total
  unsigned v = ((unsigned*)ht)[idx];
  int c0 = (int)((idx*2) & 511);
  float x0 = bfraw2f(v << 16);
  float x1 = bfraw2f(v & 0xffff0000u);
  float y0 = x0 * ss[c0]   + ss[512+c0];
  float y1 = x1 * ss[c0+1] + ss[512+c0+1];
  y0 = y0 > 0.f ? y0 : 0.f;
  y1 = y1 > 0.f ? y1 : 0.f;
  unsigned p0 = (unsigned)(unsigned short)f2bf(y0);
  unsigned p1 = (unsigned)(unsigned short)f2bf(y1);
  ((unsigned*)ht)[idx] = p0 | (p1 << 16);
}

// ---------------------------------------------------------------------------
extern "C" void kernel_launch(void* const* d_in, const int* in_sizes, int n_in,
                              void* d_out, int out_size, void* d_ws, size_t ws_size,
                              hipStream_t stream)
{
  const float* m1    = (const float*)d_in[0];
  const float* m2    = (const float*)d_in[1];
  const float* wq    = (const float*)d_in[2];
  const float* bq    = (const float*)d_in[3];
  const float* wk    = (const float*)d_in[4];
  const float* bk    = (const float*)d_in[5];
  const float* wv    = (const float*)d_in[6];
  const float* bv    = (const float*)d_in[7];
  const float* wm    = (const float*)d_in[8];
  const float* bm    = (const float*)d_in[9];
  const float* w1    = (const float*)d_in[10];
  const float* b1    = (const float*)d_in[11];
  const float* gamma = (const float*)d_in[12];
  const float* beta  = (const float*)d_in[13];
  const float* w2    = (const float*)d_in[14];
  const float* b2    = (const float*)d_in[15];

  char* ws = (char*)d_ws;
  size_t o = 0;
  short* XT1 = (short*)(ws + o); o += (size_t)NT_*512*2;     // 33.55 MB concat [b,n,512]
  short* MT2 = (short*)(ws + o); o += (size_t)NT_*256*2;     // 16.78 MB
  size_t qoff = o;
  short* QB  = (short*)(ws + o); o += (size_t)NT_*256*2;     // [B,H,N,D]
  short* KB  = (short*)(ws + o); o += (size_t)NT_*256*2;     // [B,H,M,D]
  short* VB  = (short*)(ws + o); o += (size_t)NT_*256*2;     // [B,C,M]
  short* HT  = (short*)(ws + qoff);                          // alias QB+KB (33.55 MB)
  short* WQ  = (short*)(ws + o); o += 256*256*2;
  short* WK  = (short*)(ws + o); o += 256*256*2;
  short* WV  = (short*)(ws + o); o += 256*256*2;
  short* W2B = (short*)(ws + o); o += 256*512*2;
  short* WCAT= (short*)(ws + o); o += 512*512*2;
  float* BEFF= (float*)(ws + o); o += 512*4;
  float* STATS=(float*)(ws + o); o += 1024*4;
  float* SS  = (float*)(ws + o); o += 1024*4;
  if (ws_size < o) return;   // insufficient workspace; bail (output stays poisoned)

  prep_wcat<<<512, 256, 0, stream>>>(w1, wm, b1, bm, WCAT, BEFF, STATS);
  cvt4_bf16<<<1280, 256, 0, stream>>>(wq, wk, wv, w2, WQ, WK, WV, W2B);
  transpose_cvt<<<dim3(128, 8, 16), 256, 0, stream>>>(m1, m2, XT1, MT2);

  // Q pre-scaled by log2(e)/8 so flash uses exp2 directly
  gemm_bt<0><<<dim3(32, 2, 8), 256, 0, stream>>>(WQ, 256, XT1, 512, bq, 0.18033688f, 256, QB, nullptr);
  gemm_bt<0><<<dim3(32, 2, 8), 256, 0, stream>>>(WK, 256, MT2, 256, bk, 1.0f,        256, KB, nullptr);
  gemm_bt<1><<<dim3(32, 2, 8), 256, 0, stream>>>(WV, 256, MT2, 256, bv, 1.0f,        256, VB, nullptr);

  flash_attn<<<dim3(32, 32), 256, 0, stream>>>(QB, KB, VB, XT1);

  gemm_bt<2><<<dim3(256, 4, 1), 256, 0, stream>>>(WCAT, 512, XT1, 512, BEFF, 1.0f, 512, HT, nullptr);
  bn_stats<<<128, 256, 0, stream>>>(HT, STATS);
  bn_final<<<2, 256, 0, stream>>>(STATS, gamma, beta, SS);
  relu_affine<<<32768, 256, 0, stream>>>(HT, SS);
  gemm_bt<3><<<dim3(256, 2, 1), 256, 0, stream>>>(W2B, 512, HT, 512, b2, 1.0f, 512, d_out, m1);
}

// Round 5
// 418.677 us; speedup vs baseline: 1.1853x; 1.1853x over previous
//
#include <hip/hip_runtime.h>
#include <stdint.h>

#define B_  8
#define C_  256
#define H_  4
#define D_  64
#define N_  4096
#define C2_ 512
#define NT_ (B_*N_)   // 32768 total (b,n) columns

typedef __attribute__((ext_vector_type(8))) short short8;
typedef __attribute__((ext_vector_type(4))) short short4_t;
typedef __attribute__((ext_vector_type(4))) float f32x4;

__device__ __forceinline__ short f2bf(float f) {
  union { float f; unsigned u; } v; v.f = f;
  unsigned r = v.u + 0x7fffu + ((v.u >> 16) & 1u);
  return (short)(r >> 16);
}
__device__ __forceinline__ float bfraw2f(unsigned hi_bits) {
  union { unsigned u; float f; } v; v.u = hi_bits;
  return v.f;
}
__device__ __forceinline__ unsigned fbits(float f) {
  union { float f; unsigned u; } v; v.f = f; return v.u;
}

#if __has_builtin(__builtin_amdgcn_exp2f)
#define EXP2(x) __builtin_amdgcn_exp2f(x)
#else
#define EXP2(x) exp2f(x)
#endif

#define GLOAD16(g, l) __builtin_amdgcn_global_load_lds( \
    (const __attribute__((address_space(1))) void*)(g), \
    (__attribute__((address_space(3))) void*)(l), 16, 0, 0)

// ---------------------------------------------------------------------------
// Weight prep: Wcat = [w1a | w1b@wm] bf16, beff = b1 + w1b@bm, zero stats
// ---------------------------------------------------------------------------
__global__ __launch_bounds__(256) void prep_wcat(
    const float* __restrict__ w1, const float* __restrict__ wm,
    const float* __restrict__ b1, const float* __restrict__ bm,
    short* __restrict__ wcat, float* __restrict__ beff, float* __restrict__ stats)
{
  int i = blockIdx.x, j = threadIdx.x;
  wcat[(size_t)i*512 + j] = f2bf(w1[(size_t)i*512 + j]);
  float acc = 0.f;
  for (int c = 0; c < 256; ++c)
    acc += w1[(size_t)i*512 + 256 + c] * wm[(size_t)c*256 + j];
  wcat[(size_t)i*512 + 256 + j] = f2bf(acc);
  if (j == 0) {
    float a = b1[i];
    for (int c = 0; c < 256; ++c) a += w1[(size_t)i*512 + 256 + c] * bm[c];
    beff[i] = a;
  }
  if (blockIdx.x < 4) stats[blockIdx.x*256 + j] = 0.f;
}

// one launch for all four weight conversions (wq/wk/wv = 65536, w2 = 131072)
__global__ __launch_bounds__(256) void cvt4_bf16(
    const float* __restrict__ s0, const float* __restrict__ s1,
    const float* __restrict__ s2, const float* __restrict__ s3,
    short* __restrict__ d0, short* __restrict__ d1,
    short* __restrict__ d2, short* __restrict__ d3)
{
  int i = blockIdx.x*256 + threadIdx.x;
  if (i < 65536)        d0[i]          = f2bf(s0[i]);
  else if (i < 131072)  d1[i - 65536]  = f2bf(s1[i - 65536]);
  else if (i < 196608)  d2[i - 131072] = f2bf(s2[i - 131072]);
  else                  d3[i - 196608] = f2bf(s3[i - 196608]);
}

// ---------------------------------------------------------------------------
// Transpose+convert: m1[b,c,n] -> xt1[b,n,c] (ld 512, low 256), m2 -> mt2 (ld 256)
// ---------------------------------------------------------------------------
__global__ __launch_bounds__(256) void transpose_cvt(
    const float* __restrict__ m1, const float* __restrict__ m2,
    short* __restrict__ xt1, short* __restrict__ mt2)
{
  __shared__ float tile[32][33];
  int z = blockIdx.z;            // 0..15
  int b = z >> 1, which = z & 1;
  const float* src = which ? m2 : m1;
  short* dst = which ? mt2 : xt1;
  int ldd = which ? 256 : 512;
  int c0 = blockIdx.y*32, n0 = blockIdx.x*32;
  int tx = threadIdx.x & 31, ty = threadIdx.x >> 5;   // ty 0..7
  for (int r = 0; r < 4; ++r) {
    int c = c0 + ty + r*8;
    tile[ty + r*8][tx] = src[((size_t)b*256 + c)*4096 + n0 + tx];
  }
  __syncthreads();
  for (int r = 0; r < 4; ++r) {
    int n = n0 + ty + r*8;
    dst[((size_t)b*4096 + n)*ldd + c0 + tx] = f2bf(tile[tx][ty + r*8]);
  }
}

// ---------------------------------------------------------------------------
// Generic 128x128-tile bf16 GEMM, B^T form: Out[i,j] = sum_k A[i,k]*B[j,k]+bias[i]
// MODE 0: QK projection -> out[( (i>>6)*4096 + j)*64 + (i&63)]  (per-batch z), *scale
//         coalesced via LDS C-tile transpose
// MODE 1: V projection  -> out[i*4096 + j]                      (per-batch z)
// MODE 2: h GEMM        -> out[j*512 + i]  coalesced via LDS C-tile transpose
// MODE 3: final         -> fp32 out[((j>>12)*256+i)*4096 + (j&4095)] += resid
// ---------------------------------------------------------------------------
template<int MODE>
__global__ __launch_bounds__(256) void gemm_bt(
    const short* __restrict__ A, int lda,
    const short* __restrict__ Bm, int ldb,
    const float* __restrict__ bias, float scale, int Kc,
    void* __restrict__ OutP, const float* __restrict__ resid)
{
  __shared__ __align__(16) short smem[2*128*64];
  short* As = smem;
  short* Bs = smem + 128*64;
  const int tid  = threadIdx.x;
  const int wave = tid >> 6, lane = tid & 63;
  const int it = blockIdx.y, jt = blockIdx.x, bz = blockIdx.z;
  const int i0 = it*128, j0 = jt*128;
  const short* Bb = Bm + (size_t)bz * 4096 * ldb;   // z only used for MODE 0/1
  const int wi = wave >> 1, wj = wave & 1;
  const int l15 = lane & 15, lg = lane >> 4;

  f32x4 acc[4][4] = {};

  for (int k0 = 0; k0 < Kc; k0 += 64) {
    __syncthreads();
    for (int s = 0; s < 4; ++s) {
      int flat = s*256 + tid;
      int row = flat >> 3, l8 = flat & 7;
      GLOAD16(A  + (size_t)(i0 + row)*lda + k0 + l8*8, &As[(s*256 + wave*64)*8]);
      GLOAD16(Bb + (size_t)(j0 + row)*ldb + k0 + l8*8, &Bs[(s*256 + wave*64)*8]);
    }
    __syncthreads();
    for (int ks = 0; ks < 2; ++ks) {
      short8 af[4], bf[4];
      for (int mt = 0; mt < 4; ++mt)
        af[mt] = *(const short8*)&As[(wi*64 + mt*16 + l15)*64 + ks*32 + lg*8];
      for (int nt = 0; nt < 4; ++nt)
        bf[nt] = *(const short8*)&Bs[(wj*64 + nt*16 + l15)*64 + ks*32 + lg*8];
      for (int mt = 0; mt < 4; ++mt)
        for (int nt = 0; nt < 4; ++nt)
          acc[mt][nt] = __builtin_amdgcn_mfma_f32_16x16x32_bf16(af[mt], bf[nt], acc[mt][nt], 0, 0, 0);
    }
  }

  if (MODE == 0 || MODE == 2) {
    // stage bf16 C-tile in LDS as [j][i] (16 chunks of 8 i, chunk-XOR swizzled),
    // then fully-coalesced short8 stores.
    __syncthreads();
    for (int mt = 0; mt < 4; ++mt) {
      int iL = wi*64 + mt*16 + lg*4;
      short4_t s4;
      for (int nt = 0; nt < 4; ++nt) {
        int jL = wj*64 + nt*16 + l15;
        for (int r = 0; r < 4; ++r) {
          float v = acc[mt][nt][r] + bias[i0 + iL + r];
          if (MODE == 0) v *= scale;
          s4[r] = f2bf(v);
        }
        int ic8 = iL >> 3, half = (iL >> 2) & 1;
        *(short4_t*)&smem[(jL*16 + (ic8 ^ (jL & 15)))*8 + half*4] = s4;
      }
    }
    __syncthreads();
    int ic8 = tid & 15, jj = tid >> 4;
    for (int pass = 0; pass < 8; ++pass) {
      int j = pass*16 + jj;
      short8 val = *(const short8*)&smem[(j*16 + (ic8 ^ (j & 15)))*8];
      if (MODE == 0) {
        int hh = (i0 >> 6) + (ic8 >> 3);
        int d  = (ic8 & 7) * 8;
        short* out = (short*)OutP + (size_t)bz*C_*N_;
        *(short8*)&out[((size_t)hh*4096 + (j0 + j))*64 + d] = val;
      } else {
        *(short8*)&((short*)OutP)[(size_t)(j0 + j)*512 + i0 + ic8*8] = val;
      }
    }
  } else {
    for (int mt = 0; mt < 4; ++mt)
      for (int nt = 0; nt < 4; ++nt)
        for (int r = 0; r < 4; ++r) {
          int i = i0 + wi*64 + mt*16 + lg*4 + r;
          int j = j0 + wj*64 + nt*16 + l15;
          float v = acc[mt][nt][r] + bias[i];
          if (MODE == 1) {
            short* out = (short*)OutP + (size_t)bz*C_*N_;
            out[(size_t)i*4096 + j] = f2bf(v);
          } else {
            size_t oi = ((size_t)(j >> 12)*256 + i)*4096 + (j & 4095);
            ((float*)OutP)[oi] = v + resid[oi];
          }
        }
  }
}

// ---------------------------------------------------------------------------
// Flash attention v3 (best known): grid (N/256, B*H), 256 thr = 4 waves x 64 q.
// S^T = K·Q^T (P exits MFMA in A-fragment form). K/V double-buffered in LDS,
// XOR-swizzled chunks (conflict-free). Q pre-scaled by log2(e)/8 -> exp2.
// ---------------------------------------------------------------------------
__global__ __launch_bounds__(256, 2) void flash_attn(
    const short* __restrict__ qb, const short* __restrict__ kb,
    const short* __restrict__ vb, short* __restrict__ xt1)
{
  __shared__ __align__(16) short K_lds[2][64*64];   // chunk (row,dc) at row*8 + (dc ^ (row&7))
  __shared__ __align__(16) short V_lds[2][64*64];   // chunk (d,mc)  at d*8 + (mc ^ (d&7))
  const int tid = threadIdx.x, wave = tid >> 6, lane = tid & 63;
  const int l15 = lane & 15, lg = lane >> 4;
  const int bh = blockIdx.y, qt = blockIdx.x;
  const int b = bh >> 2, h = bh & 3;
  const short* qbase = qb + (size_t)bh*4096*64;
  const short* kbase = kb + (size_t)bh*4096*64;
  const short* vbase = vb + ((size_t)b*256 + h*64)*4096;
  const int q0 = qt*256 + wave*64;

  // staging addresses (chunk c = s*256 + tid), swizzle x = (c&7) ^ (row&7)
  int c0 = tid, c1 = 256 + tid;
  int row0 = c0 >> 3, x0 = (c0 & 7) ^ (row0 & 7);
  int row1 = c1 >> 3, x1 = (c1 & 7) ^ (row1 & 7);
  const short* kg0 = kbase + row0*64 + x0*8;
  const short* kg1 = kbase + row1*64 + x1*8;
  const short* vg0 = vbase + (size_t)row0*4096 + x0*8;
  const short* vg1 = vbase + (size_t)row1*4096 + x1*8;
  const unsigned ldsA = (unsigned)((wave*64)*8);
  const unsigned ldsB = (unsigned)((256 + wave*64)*8);

  // loop-invariant LDS read offsets
  unsigned kOff[4][2];
  for (int ct = 0; ct < 4; ++ct) {
    int row = ct*16 + l15;
    for (int hf = 0; hf < 2; ++hf)
      kOff[ct][hf] = (unsigned)(row*64 + (((hf*4 + lg) ^ (row & 7))*8));
  }
  unsigned vOff[2][4][2];
  for (int p = 0; p < 2; ++p)
    for (int dt = 0; dt < 4; ++dt) {
      int d = dt*16 + l15;
      int mc1 = p*4 + (lg >> 1), mc2 = mc1 + 2;
      vOff[p][dt][0] = (unsigned)((d*8 + (mc1 ^ (d & 7)))*8 + (lg & 1)*4);
      vOff[p][dt][1] = (unsigned)((d*8 + (mc2 ^ (d & 7)))*8 + (lg & 1)*4);
    }

  short8 qf[4][2];
  for (int rt = 0; rt < 4; ++rt) {
    int q = q0 + rt*16 + l15;
    for (int hf = 0; hf < 2; ++hf)
      qf[rt][hf] = *(const short8*)(qbase + (size_t)q*64 + hf*32 + lg*8);
  }

  f32x4 o[4][4] = {};          // [rt][dt]: rows q=lg*4+r, col d=l15
  f32x4 rs4[4] = {};

  // preload tile 0 into buffer 0
  GLOAD16(kg0, &K_lds[0][ldsA]);
  GLOAD16(kg1, &K_lds[0][ldsB]);
  GLOAD16(vg0, &V_lds[0][ldsA]);
  GLOAD16(vg1, &V_lds[0][ldsB]);

  for (int itv = 0; itv < 64; ++itv) {
    __syncthreads();   // drains this wave's in-flight loads => buf[cur] ready for all
    const int cur = itv & 1, nxt = cur ^ 1;
    const size_t mN = (size_t)(((itv + 1) & 63) * 64);  // wraps to 0 on last iter (harmless refetch)
    GLOAD16(kg0 + mN*64, &K_lds[nxt][ldsA]);
    GLOAD16(kg1 + mN*64, &K_lds[nxt][ldsB]);
    GLOAD16(vg0 + mN,    &V_lds[nxt][ldsA]);
    GLOAD16(vg1 + mN,    &V_lds[nxt][ldsB]);

    const short* Kb = &K_lds[cur][0];
    const short* Vb = &V_lds[cur][0];

    // K fragments: lane row m = ct*16+l15, d-chunk deswizzled
    short8 kf[4][2];
    for (int ct = 0; ct < 4; ++ct)
      for (int hf = 0; hf < 2; ++hf)
        kf[ct][hf] = *(const short8*)(Kb + kOff[ct][hf]);
    // V fragments: lane d = dt*16+l15; k-slot (lg,j) -> m = p*32+(j>>2)*16+lg*4+(j&3)
    short8 vf[2][4];
    for (int p = 0; p < 2; ++p)
      for (int dt = 0; dt < 4; ++dt) {
        union { short8 v; short4_t h[2]; } u;
        u.h[0] = *(const short4_t*)(Vb + vOff[p][dt][0]);
        u.h[1] = *(const short4_t*)(Vb + vOff[p][dt][1]);
        vf[p][dt] = u.v;
      }

    for (int rt = 0; rt < 4; ++rt) {
      // S^T tiles: D[m][q], lane col q=l15, rows m=ct*16+lg*4+r
      f32x4 sc[4];
      for (int ct = 0; ct < 4; ++ct) {
        f32x4 s = {0.f, 0.f, 0.f, 0.f};
        s = __builtin_amdgcn_mfma_f32_16x16x32_bf16(kf[ct][0], qf[rt][0], s, 0, 0, 0);
        s = __builtin_amdgcn_mfma_f32_16x16x32_bf16(kf[ct][1], qf[rt][1], s, 0, 0, 0);
        sc[ct] = s;
      }
      // exp2 + rowsum + truncating pack into A-fragments (k-perm matches vf)
      for (int p = 0; p < 2; ++p) {
        union { short8 v; unsigned u[4]; } pf;
        for (int idx = 0; idx < 2; ++idx) {
          f32x4 sv = sc[2*p + idx];
          f32x4 ev;
          ev[0] = EXP2(sv[0]); ev[1] = EXP2(sv[1]);
          ev[2] = EXP2(sv[2]); ev[3] = EXP2(sv[3]);
          rs4[rt] += ev;
          pf.u[idx*2 + 0] = __builtin_amdgcn_perm(fbits(ev[1]), fbits(ev[0]), 0x07060302u);
          pf.u[idx*2 + 1] = __builtin_amdgcn_perm(fbits(ev[3]), fbits(ev[2]), 0x07060302u);
        }
        for (int dt = 0; dt < 4; ++dt)
          o[rt][dt] = __builtin_amdgcn_mfma_f32_16x16x32_bf16(pf.v, vf[p][dt], o[rt][dt], 0, 0, 0);
      }
    }
  }

  // reduce rowsums across lg (each lane: q = l15 within its rt tile)
  float rsI[4];
  for (int rt = 0; rt < 4; ++rt) {
    float v = (rs4[rt][0] + rs4[rt][1]) + (rs4[rt][2] + rs4[rt][3]);
    v += __shfl_xor(v, 16);
    v += __shfl_xor(v, 32);
    rsI[rt] = 1.0f / v;
  }
  for (int rt = 0; rt < 4; ++rt) {
    float invq[4];
    for (int r = 0; r < 4; ++r) invq[r] = __shfl(rsI[rt], lg*4 + r);
    for (int dt = 0; dt < 4; ++dt)
      for (int r = 0; r < 4; ++r) {
        int q = q0 + rt*16 + lg*4 + r;
        int d = dt*16 + l15;
        float val = o[rt][dt][r] * invq[r];
        xt1[((size_t)b*4096 + q)*512 + 256 + h*64 + d] = f2bf(val);
      }
  }
}

// ---------------------------------------------------------------------------
// BN stats: per-channel sum/sumsq over 32768 rows of h_t[32768][512]
// ---------------------------------------------------------------------------
__global__ __launch_bounds__(256) void bn_stats(const short* __restrict__ ht,
                                                float* __restrict__ stats)
{
  int p = blockIdx.x, t = threadIdx.x;
  int c0 = t*2;
  float s0=0.f, s1=0.f, q0=0.f, q1=0.f;
  for (int r = 0; r < 64; ++r) {
    size_t row = (size_t)p*64 + r;
    unsigned v = *(const unsigned*)&ht[row*512 + c0];
    float x0 = bfraw2f(v << 16);
    float x1 = bfraw2f(v & 0xffff0000u);
    s0 += x0; q0 += x0*x0; s1 += x1; q1 += x1*x1;
  }
  atomicAdd(&stats[c0],       s0);
  atomicAdd(&stats[c0+1],     s1);
  atomicAdd(&stats[512+c0],   q0);
  atomicAdd(&stats[512+c0+1], q1);
}

__global__ void bn_final(const float* __restrict__ stats,
                         const float* __restrict__ gamma, const float* __restrict__ beta,
                         float* __restrict__ ss)
{
  int c = blockIdx.x*256 + threadIdx.x;
  if (c >= 512) return;
  float mean = stats[c] * (1.f/32768.f);
  float var  = stats[512+c] * (1.f/32768.f) - mean*mean;
  float sc = gamma[c] * rsqrtf(var + 1e-5f);
  ss[c] = sc;
  ss[512+c] = beta[c] - mean*sc;
}

__global__ __launch_bounds__(256) void relu_affine(short* __restrict__ ht,
                                                   const float* __restrict__ ss)
{
  size_t idx = (size_t)blockIdx.x*256 + threadIdx.x;   // pairs; 8388608 total
  unsigned v = ((unsigned*)ht)[idx];
  int c0 = (int)((idx*2) & 511);
  float x0 = bfraw2f(v << 16);
  float x1 = bfraw2f(v & 0xffff0000u);
  float y0 = x0 * ss[c0]   + ss[512+c0];
  float y1 = x1 * ss[c0+1] + ss[512+c0+1];
  y0 = y0 > 0.f ? y0 : 0.f;
  y1 = y1 > 0.f ? y1 : 0.f;
  unsigned p0 = (unsigned)(unsigned short)f2bf(y0);
  unsigned p1 = (unsigned)(unsigned short)f2bf(y1);
  ((unsigned*)ht)[idx] = p0 | (p1 << 16);
}

// ---------------------------------------------------------------------------
extern "C" void kernel_launch(void* const* d_in, const int* in_sizes, int n_in,
                              void* d_out, int out_size, void* d_ws, size_t ws_size,
                              hipStream_t stream)
{
  const float* m1    = (const float*)d_in[0];
  const float* m2    = (const float*)d_in[1];
  const float* wq    = (const float*)d_in[2];
  const float* bq    = (const float*)d_in[3];
  const float* wk    = (const float*)d_in[4];
  const float* bk    = (const float*)d_in[5];
  const float* wv    = (const float*)d_in[6];
  const float* bv    = (const float*)d_in[7];
  const float* wm    = (const float*)d_in[8];
  const float* bm    = (const float*)d_in[9];
  const float* w1    = (const float*)d_in[10];
  const float* b1    = (const float*)d_in[11];
  const float* gamma = (const float*)d_in[12];
  const float* beta  = (const float*)d_in[13];
  const float* w2    = (const float*)d_in[14];
  const float* b2    = (const float*)d_in[15];

  char* ws = (char*)d_ws;
  size_t o = 0;
  short* XT1 = (short*)(ws + o); o += (size_t)NT_*512*2;     // 33.55 MB concat [b,n,512]
  short* MT2 = (short*)(ws + o); o += (size_t)NT_*256*2;     // 16.78 MB
  size_t qoff = o;
  short* QB  = (short*)(ws + o); o += (size_t)NT_*256*2;     // [B,H,N,D]
  short* KB  = (short*)(ws + o); o += (size_t)NT_*256*2;     // [B,H,M,D]
  short* VB  = (short*)(ws + o); o += (size_t)NT_*256*2;     // [B,C,M]
  short* HT  = (short*)(ws + qoff);                          // alias QB+KB (33.55 MB)
  short* WQ  = (short*)(ws + o); o += 256*256*2;
  short* WK  = (short*)(ws + o); o += 256*256*2;
  short* WV  = (short*)(ws + o); o += 256*256*2;
  short* W2B = (short*)(ws + o); o += 256*512*2;
  short* WCAT= (short*)(ws + o); o += 512*512*2;
  float* BEFF= (float*)(ws + o); o += 512*4;
  float* STATS=(float*)(ws + o); o += 1024*4;
  float* SS  = (float*)(ws + o); o += 1024*4;
  if (ws_size < o) return;   // insufficient workspace; bail (output stays poisoned)

  prep_wcat<<<512, 256, 0, stream>>>(w1, wm, b1, bm, WCAT, BEFF, STATS);
  cvt4_bf16<<<1280, 256, 0, stream>>>(wq, wk, wv, w2, WQ, WK, WV, W2B);
  transpose_cvt<<<dim3(128, 8, 16), 256, 0, stream>>>(m1, m2, XT1, MT2);

  // Q pre-scaled by log2(e)/8 so flash uses exp2 directly
  gemm_bt<0><<<dim3(32, 2, 8), 256, 0, stream>>>(WQ, 256, XT1, 512, bq, 0.18033688f, 256, QB, nullptr);
  gemm_bt<0><<<dim3(32, 2, 8), 256, 0, stream>>>(WK, 256, MT2, 256, bk, 1.0f,        256, KB, nullptr);
  gemm_bt<1><<<dim3(32, 2, 8), 256, 0, stream>>>(WV, 256, MT2, 256, bv, 1.0f,        256, VB, nullptr);

  flash_attn<<<dim3(16, 32), 256, 0, stream>>>(QB, KB, VB, XT1);

  gemm_bt<2><<<dim3(256, 4, 1), 256, 0, stream>>>(WCAT, 512, XT1, 512, BEFF, 1.0f, 512, HT, nullptr);
  bn_stats<<<512, 256, 0, stream>>>(HT, STATS);
  bn_final<<<2, 256, 0, stream>>>(STATS, gamma, beta, SS);
  relu_affine<<<32768, 256, 0, stream>>>(HT, SS);
  gemm_bt<3><<<dim3(256, 2, 1), 256, 0, stream>>>(W2B, 512, HT, 512, b2, 1.0f, 512, d_out, m1);
}